// Round 8
// baseline (468.787 us; speedup 1.0000x reference)
//
#include <hip/hip_runtime.h>
#include <hip/hip_bf16.h>
#include <math.h>

typedef __bf16 bf16;
typedef __bf16 bf16x8 __attribute__((ext_vector_type(8)));
typedef float f32x4 __attribute__((ext_vector_type(4)));

__device__ __forceinline__ void gload_lds16(const bf16* g, bf16* l) {
  __builtin_amdgcn_global_load_lds(
      (const __attribute__((address_space(1))) void*)g,
      (__attribute__((address_space(3))) void*)l, 16, 0, 0);
}

#define MF(a, b, c) __builtin_amdgcn_mfma_f32_16x16x32_bf16((a), (b), (c), 0, 0, 0)
// fused wait+barrier / barrier+wait as single opaque asm: no memory op
// (ds_read or global_load_lds) can be scheduled across them.
#define BAR_LGK()   asm volatile("s_barrier\ns_waitcnt lgkmcnt(0)" ::: "memory")
#define BAR_ONLY()  asm volatile("s_barrier" ::: "memory")
#define VM4_BAR()   asm volatile("s_waitcnt vmcnt(4)\ns_barrier" ::: "memory")
#define VM0_BAR()   asm volatile("s_waitcnt vmcnt(0)\ns_barrier" ::: "memory")

// 256x256 8-wave GEMM, BK=64 as two K-halves, double-buffered LDS,
// per-phase staging with counted vmcnt(4) (never 0 mid-loop), hoisted
// addresses, chunk-XOR swizzle, setprio. Per-wave out 128x64 (acc[8][4]).
// C = A[M,K] @ BT[N,K]^T.
// EPI 0: bf16 = acc+bias | 1: f32 = acc+bias+res | 2: bf16 = gelu(acc+bias)
// EPI 3: bf16 = acc (raw partial; KSPLIT=2: ks0->Cout, ks1->Cout2)
template <int EPI, int KSPLIT>
__global__ __launch_bounds__(512, 2)
void gemm8(const bf16* __restrict__ A, const bf16* __restrict__ BT,
           const float* __restrict__ bias, const float* __restrict__ res,
           void* __restrict__ Cout, void* __restrict__ Cout2,
           int M, int N, int K)
{
  __shared__ alignas(16) bf16 lsA[2][2][8192];   // [buf][khalf][256*32]
  __shared__ alignas(16) bf16 lsB[2][2][8192];

  int nbn = N >> 8;
  int nwg = (M >> 8) * nbn;
  int bid = blockIdx.x;
  int ks = 0;
  if (KSPLIT == 2) { ks = (bid >= nwg) ? 1 : 0; bid -= ks * nwg; }
  int cpx = nwg >> 3;
  int wg  = (bid & 7) * cpx + (bid >> 3);       // XCD swizzle (bijective)
  int m0 = (wg / nbn) << 8;
  int n0 = (wg % nbn) << 8;

  int t = threadIdx.x;
  int l = t & 63, w = t >> 6;
  int wm = (w >> 2) << 7;        // 0 / 128
  int wn = (w & 3) << 6;         // 0 / 64 / 128 / 192
  int lr = l & 15, lg = l >> 4;

  int kbase = (KSPLIT == 2) ? ks * (K >> 1) : 0;
  int nt = (K / KSPLIT) >> 6;

  const bf16* Ag = A  + (size_t)m0 * K + kbase;
  const bf16* Bg = BT + (size_t)n0 * K + kbase;

  // hoisted ds_read offsets; swizzle term is rep-invariant (row bits 0..3 = lr)
  int s_lane = (lr & 3) ^ ((lr >> 2) & 3);
  int aoffE = (wm + lr) * 32 + ((lg ^ s_lane) << 3);
  int boffE = (wn + lr) * 32 + ((lg ^ s_lane) << 3);

  // hoisted staging addresses: 2 chunks per khalf-subtile per thread;
  // linear LDS dest (lane x 16B), inverse-swizzled global source (G21)
  const bf16* srcA[2]; const bf16* srcB[2]; int dstE[2];
#pragma unroll
  for (int j = 0; j < 2; ++j) {
    int ci = j * 512 + t;
    int row = ci >> 2;
    int g = (ci & 3) ^ ((row & 3) ^ ((row >> 2) & 3));
    srcA[j] = Ag + (size_t)row * K + g * 8;
    srcB[j] = Bg + (size_t)row * K + g * 8;
    dstE[j] = ci * 8;
  }

  f32x4 acc[8][4];
  f32x4 zero = {0.f, 0.f, 0.f, 0.f};
#pragma unroll
  for (int mi = 0; mi < 8; ++mi)
#pragma unroll
    for (int ni = 0; ni < 4; ++ni) acc[mi][ni] = zero;

  // prologue: tile 0 = A-k0, B-k0, A-k1, B-k1 (2 loads each, this order)
#pragma unroll
  for (int j = 0; j < 2; ++j) gload_lds16(srcA[j],      &lsA[0][0][0] + dstE[j]);
#pragma unroll
  for (int j = 0; j < 2; ++j) gload_lds16(srcB[j],      &lsB[0][0][0] + dstE[j]);
#pragma unroll
  for (int j = 0; j < 2; ++j) gload_lds16(srcA[j] + 32, &lsA[0][1][0] + dstE[j]);
#pragma unroll
  for (int j = 0; j < 2; ++j) gload_lds16(srcB[j] + 32, &lsB[0][1][0] + dstE[j]);
  VM4_BAR();                     // khalf0 resident; khalf1 in flight

  for (int T = 0; T < nt; ++T) {
    int cb = T & 1;
    const bf16* pa = &lsA[cb][0][0];
    const bf16* pb = &lsB[cb][0][0];
    bf16* sa = &lsA[cb ^ 1][0][0];
    bf16* sb = &lsB[cb ^ 1][0][0];
    bool st = (T + 1 < nt);
    int k64 = (T + 1) << 6;

    bf16x8 afr[8], bf0, bf1, bf2, bf3;

    // ---------- phase 0: khalf0, n0-1; stage A-k0(T+1) ----------
#pragma unroll
    for (int mi = 0; mi < 8; ++mi)
      afr[mi] = *(const bf16x8*)(pa + aoffE + mi * 512);
    bf0 = *(const bf16x8*)(pb + boffE);
    bf1 = *(const bf16x8*)(pb + boffE + 512);
    if (st) {
#pragma unroll
      for (int j = 0; j < 2; ++j) gload_lds16(srcA[j] + k64, sa + dstE[j]);
    }
    BAR_LGK();
    __builtin_amdgcn_sched_barrier(0);
    __builtin_amdgcn_s_setprio(1);
#pragma unroll
    for (int mi = 0; mi < 8; ++mi) {
      acc[mi][0] = MF(afr[mi], bf0, acc[mi][0]);
      acc[mi][1] = MF(afr[mi], bf1, acc[mi][1]);
    }
    __builtin_amdgcn_s_setprio(0);
    BAR_ONLY();

    // ---------- phase 1: khalf0, n2-3; stage B-k0(T+1) ----------
    bf2 = *(const bf16x8*)(pb + boffE + 1024);
    bf3 = *(const bf16x8*)(pb + boffE + 1536);
    if (st) {
#pragma unroll
      for (int j = 0; j < 2; ++j) gload_lds16(srcB[j] + k64, sb + dstE[j]);
    }
    BAR_LGK();
    __builtin_amdgcn_sched_barrier(0);
    __builtin_amdgcn_s_setprio(1);
#pragma unroll
    for (int mi = 0; mi < 8; ++mi) {
      acc[mi][2] = MF(afr[mi], bf2, acc[mi][2]);
      acc[mi][3] = MF(afr[mi], bf3, acc[mi][3]);
    }
    __builtin_amdgcn_s_setprio(0);
    // W1: khalf1 of THIS tile resident after this barrier (all waves)
    if (st) VM4_BAR(); else VM0_BAR();

    // ---------- phase 2: khalf1, n0-1; stage A-k1(T+1) ----------
#pragma unroll
    for (int mi = 0; mi < 8; ++mi)
      afr[mi] = *(const bf16x8*)(pa + 8192 + aoffE + mi * 512);
    bf0 = *(const bf16x8*)(pb + 8192 + boffE);
    bf1 = *(const bf16x8*)(pb + 8192 + boffE + 512);
    if (st) {
#pragma unroll
      for (int j = 0; j < 2; ++j) gload_lds16(srcA[j] + k64 + 32, sa + 8192 + dstE[j]);
    }
    BAR_LGK();
    __builtin_amdgcn_sched_barrier(0);
    __builtin_amdgcn_s_setprio(1);
#pragma unroll
    for (int mi = 0; mi < 8; ++mi) {
      acc[mi][0] = MF(afr[mi], bf0, acc[mi][0]);
      acc[mi][1] = MF(afr[mi], bf1, acc[mi][1]);
    }
    __builtin_amdgcn_s_setprio(0);
    BAR_ONLY();

    // ---------- phase 3: khalf1, n2-3; stage B-k1(T+1) ----------
    bf2 = *(const bf16x8*)(pb + 8192 + boffE + 1024);
    bf3 = *(const bf16x8*)(pb + 8192 + boffE + 1536);
    if (st) {
#pragma unroll
      for (int j = 0; j < 2; ++j) gload_lds16(srcB[j] + k64 + 32, sb + 8192 + dstE[j]);
    }
    BAR_LGK();
    __builtin_amdgcn_sched_barrier(0);
    __builtin_amdgcn_s_setprio(1);
#pragma unroll
    for (int mi = 0; mi < 8; ++mi) {
      acc[mi][2] = MF(afr[mi], bf2, acc[mi][2]);
      acc[mi][3] = MF(afr[mi], bf3, acc[mi][3]);
    }
    __builtin_amdgcn_s_setprio(0);
    // W2: next tile's khalf0 resident after this barrier
    if (st) VM4_BAR(); else BAR_ONLY();
  }

  // epilogue
  bf16* Pb = (bf16*)((KSPLIT == 2 && ks) ? Cout2 : Cout);
#pragma unroll
  for (int mi = 0; mi < 8; ++mi) {
    int row = m0 + wm + mi * 16 + lg * 4;
#pragma unroll
    for (int ni = 0; ni < 4; ++ni) {
      int col = n0 + wn + ni * 16 + lr;
      float bv = (EPI == 3) ? 0.f : bias[col];
      f32x4 a = acc[mi][ni];
#pragma unroll
      for (int r = 0; r < 4; ++r) {
        float v = a[r] + bv;
        size_t idx = (size_t)(row + r) * N + col;
        if (EPI == 0)      Pb[idx] = (bf16)v;
        else if (EPI == 1) ((float*)Cout)[idx] = v + res[idx];
        else if (EPI == 2) Pb[idx] = (bf16)(0.5f * v * (1.f + erff(v * 0.70710678118654752f)));
        else               Pb[idx] = (bf16)v;
      }
    }
  }
}

// out = p0 + p1 + bias + res (f32), for split-K FC2. 8 elems/thread.
__global__ __launch_bounds__(256)
void combine2(const bf16* __restrict__ p0, const bf16* __restrict__ p1,
              const float* __restrict__ bias, const float* __restrict__ res,
              float* __restrict__ out)
{
  int i = (blockIdx.x * 256 + threadIdx.x) * 8;
  bf16x8 a = *(const bf16x8*)(p0 + i);
  bf16x8 b = *(const bf16x8*)(p1 + i);
  int c = i & 1023;
#pragma unroll
  for (int j = 0; j < 8; ++j)
    out[i + j] = (float)a[j] + (float)b[j] + bias[c + j] + res[i + j];
}

// LayerNorm over last dim (1024), fp32 in -> bf16 out. One block per row.
__global__ __launch_bounds__(256)
void ln_bf16(const float* __restrict__ x, const float* __restrict__ w,
             const float* __restrict__ b, bf16* __restrict__ out)
{
  int row = blockIdx.x;
  int t = threadIdx.x;
  float4 v = ((const float4*)(x + (size_t)row * 1024))[t];
  float s  = v.x + v.y + v.z + v.w;
  float sq = v.x * v.x + v.y * v.y + v.z * v.z + v.w * v.w;
#pragma unroll
  for (int off = 32; off >= 1; off >>= 1) {
    s  += __shfl_xor(s, off);
    sq += __shfl_xor(sq, off);
  }
  __shared__ float ps[4], pq[4];
  if ((t & 63) == 0) { ps[t >> 6] = s; pq[t >> 6] = sq; }
  __syncthreads();
  s  = ps[0] + ps[1] + ps[2] + ps[3];
  sq = pq[0] + pq[1] + pq[2] + pq[3];
  float mu  = s * (1.f / 1024.f);
  float var = sq * (1.f / 1024.f) - mu * mu;
  float rstd = rsqrtf(var + 1e-5f);
  float4 wv = ((const float4*)w)[t];
  float4 bv = ((const float4*)b)[t];
  size_t o0 = (size_t)row * 1024 + t * 4;
  out[o0 + 0] = (bf16)((v.x - mu) * rstd * wv.x + bv.x);
  out[o0 + 1] = (bf16)((v.y - mu) * rstd * wv.y + bv.y);
  out[o0 + 2] = (bf16)((v.z - mu) * rstd * wv.z + bv.z);
  out[o0 + 3] = (bf16)((v.w - mu) * rstd * wv.w + bv.w);
}

// WT[N,K] (bf16) = W[K,N] (f32) transposed+cast. grid=(K/32, N/32), 256 thr.
__global__ __launch_bounds__(256)
void transpose_cast(const float* __restrict__ W, bf16* __restrict__ WT, int K, int N)
{
  __shared__ float tile[32][33];
  int bk = blockIdx.x * 32, bn = blockIdx.y * 32;
  int tx = threadIdx.x & 31, ty = threadIdx.x >> 5;
#pragma unroll
  for (int i = ty; i < 32; i += 8)
    tile[i][tx] = W[(size_t)(bk + i) * N + bn + tx];
  __syncthreads();
#pragma unroll
  for (int i = ty; i < 32; i += 8)
    WT[(size_t)(bn + i) * K + bk + tx] = (bf16)tile[tx][i];
}

// V transpose: vt[(b*16+h)*64 + d][t] = qkv[(b*2048+t)*3072 + 2048 + h*64 + d]
__global__ __launch_bounds__(256)
void vtrans(const bf16* __restrict__ qkv, bf16* __restrict__ vt)
{
  __shared__ alignas(16) bf16 tile[64 * 64];
  int bh = blockIdx.x;
  int b = bh >> 4, h = bh & 15;
  int t0 = blockIdx.y * 64;
  int t = threadIdx.x;
#pragma unroll
  for (int i = 0; i < 2; ++i) {
    int c = i * 256 + t;
    int tt = c >> 3, d8 = c & 7;
    bf16x8 v = *(const bf16x8*)(qkv + (size_t)(b * 2048 + t0 + tt) * 3072 + 2048 + h * 64 + d8 * 8);
    *(bf16x8*)&tile[(tt * 8 + (d8 ^ (tt >> 3))) * 8] = v;
  }
  __syncthreads();
#pragma unroll
  for (int i = 0; i < 2; ++i) {
    int c = i * 256 + t;
    int d = c >> 3, tt8 = c & 7;
    bf16x8 o;
#pragma unroll
    for (int j = 0; j < 8; ++j) {
      int row = tt8 * 8 + j;
      o[j] = tile[(row * 8 + ((d >> 3) ^ (row >> 3))) * 8 + (d & 7)];
    }
    *(bf16x8*)(vt + (size_t)(bh * 64 + d) * 2048 + t0 + tt8 * 8) = o;
  }
}

// Flash causal attention, block-cooperative + fixed-cap softmax.
__global__ __launch_bounds__(256)
void attn_flash(const bf16* __restrict__ qkv, const bf16* __restrict__ vt,
                bf16* __restrict__ y)
{
  __shared__ alignas(16) bf16 lk[64 * 64];
  __shared__ alignas(16) bf16 lv[64 * 64];
  __shared__ alignas(16) bf16 lp[4][16 * 64];

  int bid = blockIdx.x;
  int bh = bid & 63;
  int qb = 31 - (bid >> 6);
  int b = bh >> 4, h = bh & 15;
  int t = threadIdx.x;
  int w = t >> 6, l = t & 63;
  int lr = l & 15, lg = l >> 4;
  int q0 = qb * 64;
  int qw = q0 + w * 16;
  const size_t RS = 3072;
  const float SCL = 0.18033688011112042f;   // 0.125 * log2(e)

  const bf16* qbase = qkv + (size_t)(b * 2048) * RS + h * 64;
  const bf16* kbase = qkv + (size_t)(b * 2048) * RS + 1024 + h * 64;
  const bf16* vtb   = vt + (size_t)(bh * 64) * 2048;

  bf16x8 qf[2];
#pragma unroll
  for (int kk = 0; kk < 2; ++kk)
    qf[kk] = *(const bf16x8*)(qbase + (size_t)(qw + lr) * RS + kk * 32 + lg * 8);

  f32x4 zero = {0.f, 0.f, 0.f, 0.f};
  f32x4 o[4];
#pragma unroll
  for (int ni = 0; ni < 4; ++ni) o[ni] = zero;
  float lo[4] = {0.f, 0.f, 0.f, 0.f};

  int nkb = qb + 1;
  for (int kb = 0; kb < nkb; ++kb) {
    int k0 = kb * 64;
#pragma unroll
    for (int i = 0; i < 2; ++i) {
      int c = i * 256 + t;
      int row = c >> 3, c8 = c & 7;
      int sc8 = c8 ^ (row & 7);
      gload_lds16(kbase + (size_t)(k0 + row) * RS + sc8 * 8, &lk[c * 8]);
      gload_lds16(vtb + (size_t)row * 2048 + k0 + sc8 * 8, &lv[c * 8]);
    }
    __syncthreads();

    f32x4 s[4];
#pragma unroll
    for (int j = 0; j < 4; ++j) s[j] = zero;
#pragma unroll
    for (int kk = 0; kk < 2; ++kk)
#pragma unroll
      for (int j = 0; j < 4; ++j) {
        int krow = j * 16 + lr;
        bf16x8 kf = *(const bf16x8*)&lk[krow * 64 + (((4 * kk + lg) ^ (krow & 7)) * 8)];
        s[j] = MF(qf[kk], kf, s[j]);
      }

    bool needmask = (kb == qb);
    float p[4][4];
#pragma unroll
    for (int r = 0; r < 4; ++r) {
      int tq = qw + lg * 4 + r;
#pragma unroll
      for (int j = 0; j < 4; ++j) {
        float v = s[j][r] * SCL;
        if (needmask && (k0 + j * 16 + lr > tq)) v = -1e30f;
        p[j][r] = exp2f(v);
      }
      lo[r] += (p[0][r] + p[1][r]) + (p[2][r] + p[3][r]);
    }

#pragma unroll
    for (int r = 0; r < 4; ++r) {
      int qr = lg * 4 + r;
#pragma unroll
      for (int j = 0; j < 4; ++j) {
        int ch = (2 * j + (lr >> 3)) ^ (qr & 7);
        lp[w][qr * 64 + ch * 8 + (lr & 7)] = (bf16)p[j][r];
      }
    }
    bf16x8 pa[2];
#pragma unroll
    for (int kf = 0; kf < 2; ++kf)
      pa[kf] = *(const bf16x8*)&lp[w][lr * 64 + (((4 * kf + lg) ^ (lr & 7)) * 8)];

#pragma unroll
    for (int ni = 0; ni < 4; ++ni)
#pragma unroll
      for (int kf = 0; kf < 2; ++kf) {
        int d = ni * 16 + lr;
        bf16x8 vf = *(const bf16x8*)&lv[d * 64 + (((4 * kf + lg) ^ (d & 7)) * 8)];
        o[ni] = MF(pa[kf], vf, o[ni]);
      }
    __syncthreads();
  }

#pragma unroll
  for (int r = 0; r < 4; ++r) {
#pragma unroll
    for (int off = 1; off < 16; off <<= 1) lo[r] += __shfl_xor(lo[r], off);
    lo[r] = 1.f / lo[r];
  }
#pragma unroll
  for (int ni = 0; ni < 4; ++ni)
#pragma unroll
    for (int r = 0; r < 4; ++r) {
      int tq = qw + lg * 4 + r;
      y[(size_t)(b * 2048 + tq) * 1024 + h * 64 + ni * 16 + lr] = (bf16)(o[ni][r] * lo[r]);
    }
}

extern "C" void kernel_launch(void* const* d_in, const int* in_sizes, int n_in,
                              void* d_out, int out_size, void* d_ws, size_t ws_size,
                              hipStream_t stream) {
  (void)in_sizes; (void)n_in; (void)out_size; (void)ws_size;
  const float* x      = (const float*)d_in[0];
  const float* ln1w   = (const float*)d_in[1];
  const float* ln1b   = (const float*)d_in[2];
  const float* ln2w   = (const float*)d_in[3];
  const float* ln2b   = (const float*)d_in[4];
  const float* w_attn = (const float*)d_in[5];
  const float* b_attn = (const float*)d_in[6];
  const float* w_proj = (const float*)d_in[7];
  const float* b_proj = (const float*)d_in[8];
  const float* w_fc   = (const float*)d_in[9];
  const float* b_fc   = (const float*)d_in[10];
  const float* w_fc2  = (const float*)d_in[11];
  const float* b_fc2  = (const float*)d_in[12];
  float* out = (float*)d_out;

  // workspace: h | [qkv | y] == m | x1 (vt overlays x1) | weightsT
  char* p = (char*)d_ws;
  bf16*  h     = (bf16*)p;  p += (size_t)8192 * 1024 * 2;
  bf16*  qkv   = (bf16*)p;
  bf16*  mbuf  = (bf16*)p;  p += (size_t)8192 * 3072 * 2;   // m overlays qkv+y
  bf16*  ybuf  = (bf16*)p;  p += (size_t)8192 * 1024 * 2;
  float* x1    = (float*)p; p += (size_t)8192 * 1024 * 4;
  bf16*  wqkvT = (bf16*)p;  p += (size_t)3072 * 1024 * 2;
  bf16*  wprojT= (bf16*)p;  p += (size_t)1024 * 1024 * 2;
  bf16*  wfcT  = (bf16*)p;  p += (size_t)4096 * 1024 * 2;
  bf16*  wfc2T = (bf16*)p;  p += (size_t)1024 * 4096 * 2;
  bf16*  vt    = (bf16*)x1;       // dead until proj writes x1 (after attn)
  // split-K partials (FC2): p0 over h (dead), p1 over wqkvT..wfcT (16MB, dead)
  bf16*  sp0   = h;
  bf16*  sp1   = wqkvT;

  transpose_cast<<<dim3(1024 / 32, 3072 / 32), 256, 0, stream>>>(w_attn, wqkvT, 1024, 3072);
  transpose_cast<<<dim3(1024 / 32, 1024 / 32), 256, 0, stream>>>(w_proj, wprojT, 1024, 1024);
  transpose_cast<<<dim3(1024 / 32, 4096 / 32), 256, 0, stream>>>(w_fc,   wfcT,  1024, 4096);
  transpose_cast<<<dim3(4096 / 32, 1024 / 32), 256, 0, stream>>>(w_fc2,  wfc2T, 4096, 1024);

  ln_bf16<<<8192, 256, 0, stream>>>(x, ln1w, ln1b, h);
  gemm8<0, 1><<<384, 512, 0, stream>>>(h, wqkvT, b_attn, nullptr, qkv, nullptr, 8192, 3072, 1024);
  vtrans<<<dim3(64, 32), 256, 0, stream>>>(qkv, vt);
  attn_flash<<<2048, 256, 0, stream>>>(qkv, vt, ybuf);
  gemm8<1, 1><<<128, 512, 0, stream>>>(ybuf, wprojT, b_proj, x, x1, nullptr, 8192, 1024, 1024);
  ln_bf16<<<8192, 256, 0, stream>>>(x1, ln2w, ln2b, h);
  gemm8<2, 1><<<512, 512, 0, stream>>>(h, wfcT, b_fc, nullptr, mbuf, nullptr, 8192, 4096, 1024);
  gemm8<3, 2><<<256, 512, 0, stream>>>(mbuf, wfc2T, nullptr, nullptr, sp0, sp1, 8192, 1024, 4096);
  combine2<<<4096, 256, 0, stream>>>(sp0, sp1, b_fc2, x1, out);
}

// Round 9
// 439.110 us; speedup vs baseline: 1.0676x; 1.0676x over previous
//
#include <hip/hip_runtime.h>
#include <hip/hip_bf16.h>
#include <math.h>

typedef __bf16 bf16;
typedef __bf16 bf16x8 __attribute__((ext_vector_type(8)));
typedef float f32x4 __attribute__((ext_vector_type(4)));

__device__ __forceinline__ void gload_lds16(const bf16* g, bf16* l) {
  __builtin_amdgcn_global_load_lds(
      (const __attribute__((address_space(1))) void*)g,
      (__attribute__((address_space(3))) void*)l, 16, 0, 0);
}

#define MF(a, b, c) __builtin_amdgcn_mfma_f32_16x16x32_bf16((a), (b), (c), 0, 0, 0)
// fused wait+barrier blocks (opaque: nothing can be scheduled across)
#define VM4_BAR()  asm volatile("s_waitcnt vmcnt(4)\ns_barrier" ::: "memory")
#define VM2_BAR()  asm volatile("s_waitcnt vmcnt(2)\ns_barrier" ::: "memory")
#define VM0_BAR()  asm volatile("s_waitcnt vmcnt(0)\ns_barrier" ::: "memory")
#define BAR_ONLY() asm volatile("s_barrier" ::: "memory")
#define LGK0_SB()  do { asm volatile("s_waitcnt lgkmcnt(0)" ::: "memory"); \
                        __builtin_amdgcn_sched_barrier(0); } while (0)

// 256x256 8-wave GEMM, BK=64, [256][64] LDS tiles (128B rows, attn-proven
// 0-conflict chunk-XOR swizzle), double-buffered, half-tile staging (A0,B0,
// B1,A1; 2 gloads each) consumed by C-quadrant phases (all waves on one
// quadrant/phase). Counted vmcnt(4) waits, >=3-phase load lead, no mid-loop
// drain. C = A[M,K] @ BT[N,K]^T, bf16 in, fp32 accum.
// EPI 0: bf16 = acc+bias | 1: f32 = acc+bias+res | 2: bf16 = gelu(acc+bias)
// EPI 3: bf16 = acc (raw partial; KSPLIT=2: ks0->Cout, ks1->Cout2)
template <int EPI, int KSPLIT>
__global__ __launch_bounds__(512, 2)
void gemmq(const bf16* __restrict__ A, const bf16* __restrict__ BT,
           const float* __restrict__ bias, const float* __restrict__ res,
           void* __restrict__ Cout, void* __restrict__ Cout2,
           int M, int N, int K)
{
  __shared__ alignas(16) bf16 lsA[2][16384];   // [buf][256*64]  32KB each
  __shared__ alignas(16) bf16 lsB[2][16384];

  int nbn = N >> 8;
  int nwg = (M >> 8) * nbn;
  int bid = blockIdx.x;
  int ks = 0;
  if (KSPLIT == 2) { ks = (bid >= nwg) ? 1 : 0; bid -= ks * nwg; }
  int cpx = nwg >> 3;
  int wg  = (bid & 7) * cpx + (bid >> 3);      // XCD swizzle (bijective)
  int m0 = (wg / nbn) << 8;
  int n0 = (wg % nbn) << 8;

  int t = threadIdx.x;
  int l = t & 63, w = t >> 6;
  int wr = (w >> 2) << 6;        // 0 / 64   (M within half)
  int wc = (w & 3) << 5;         // 0/32/64/96 (N within half)
  int lr = l & 15, lg = l >> 4;

  int kb0 = (KSPLIT == 2) ? ks * (K >> 1) : 0;
  int nt = (K / KSPLIT) >> 6;

  const bf16* Ag = A  + (size_t)m0 * K + kb0;
  const bf16* Bg = BT + (size_t)n0 * K + kb0;

  // ds_read element offsets: frag row = q*128 + (wr|wc) + rep*16 + lr,
  // chunk8 = (kk*4+lg) ^ (lr&7)  [attn-proven 0-conflict on 128B rows]
  int swz0 = (lg ^ (lr & 7)) << 3;     // kk=0 chunk, elements
  int swz1 = swz0 ^ 32;                // kk=1 (chunk^4)
  int aRow = (wr + lr) << 6;           // row*64 elements
  int bRow = (wc + lr) << 6;

  // staging addresses: half = 128 rows = 2 instructions x 1024B linear dest;
  // inverse-swizzled global source (G21): g = (ci&7) ^ (row&7)
  const bf16* srcA[2]; const bf16* srcB[2];
#pragma unroll
  for (int j = 0; j < 2; ++j) {
    int ci = j * 512 + t;
    int r = ci >> 3;
    int g = (ci & 7) ^ (r & 7);
    srcA[j] = Ag + (size_t)r * K + g * 8;
    srcB[j] = Bg + (size_t)r * K + g * 8;
  }
  size_t qA = (size_t)128 * K;         // A-half-1 source row offset

#define STAGE_A(q, kofs, db) do { \
  _Pragma("unroll") \
  for (int j = 0; j < 2; ++j) \
    gload_lds16(srcA[j] + (q) * qA + (kofs), &lsA[db][(q) * 8192 + (j * 512 + t) * 8]); \
} while (0)
#define STAGE_B(q, kofs, db) do { \
  _Pragma("unroll") \
  for (int j = 0; j < 2; ++j) \
    gload_lds16(srcB[j] + (q) * qA + (kofs), &lsB[db][(q) * 8192 + (j * 512 + t) * 8]); \
} while (0)

  f32x4 acc[2][2][4][2];
  f32x4 zero = {0.f, 0.f, 0.f, 0.f};
#pragma unroll
  for (int qa = 0; qa < 2; ++qa)
#pragma unroll
    for (int qb = 0; qb < 2; ++qb)
#pragma unroll
      for (int mi = 0; mi < 4; ++mi)
#pragma unroll
        for (int ni = 0; ni < 2; ++ni) acc[qa][qb][mi][ni] = zero;

  // prologue: tile 0 halves in steady-state order A0,B0,B1,A1
  STAGE_A(0, 0, 0);
  STAGE_B(0, 0, 0);
  STAGE_B(1, 0, 0);
  STAGE_A(1, 0, 0);

  bf16x8 afr[4][2], bfr[2][2];

  for (int T = 0; T < nt; ++T) {
    int c = T & 1, d = c ^ 1;
    bool st = (T + 1 < nt);
    int k64 = (T + 1) << 6;
    const bf16* pa = &lsA[c][0];
    const bf16* pb = &lsB[c][0];

    // ---- ph0: quadrant (0,0); needs A0,B0 of tile T; stage A0(T+1) ----
    VM4_BAR();
#pragma unroll
    for (int mi = 0; mi < 4; ++mi) {
      afr[mi][0] = *(const bf16x8*)(pa + aRow + mi * 1024 + swz0);
      afr[mi][1] = *(const bf16x8*)(pa + aRow + mi * 1024 + swz1);
    }
#pragma unroll
    for (int ni = 0; ni < 2; ++ni) {
      bfr[ni][0] = *(const bf16x8*)(pb + bRow + ni * 1024 + swz0);
      bfr[ni][1] = *(const bf16x8*)(pb + bRow + ni * 1024 + swz1);
    }
    if (st) STAGE_A(0, k64, d);
    LGK0_SB();
    __builtin_amdgcn_s_setprio(1);
#pragma unroll
    for (int mi = 0; mi < 4; ++mi)
#pragma unroll
      for (int ni = 0; ni < 2; ++ni)
#pragma unroll
        for (int kk = 0; kk < 2; ++kk)
          acc[0][0][mi][ni] = MF(afr[mi][kk], bfr[ni][kk], acc[0][0][mi][ni]);
    __builtin_amdgcn_s_setprio(0);

    // ---- ph1: quadrant (0,1); needs B1; stage B0(T+1) ----
    if (st) VM4_BAR(); else VM2_BAR();
#pragma unroll
    for (int ni = 0; ni < 2; ++ni) {
      bfr[ni][0] = *(const bf16x8*)(pb + 8192 + bRow + ni * 1024 + swz0);
      bfr[ni][1] = *(const bf16x8*)(pb + 8192 + bRow + ni * 1024 + swz1);
    }
    if (st) STAGE_B(0, k64, d);
    LGK0_SB();
    __builtin_amdgcn_s_setprio(1);
#pragma unroll
    for (int mi = 0; mi < 4; ++mi)
#pragma unroll
      for (int ni = 0; ni < 2; ++ni)
#pragma unroll
        for (int kk = 0; kk < 2; ++kk)
          acc[0][1][mi][ni] = MF(afr[mi][kk], bfr[ni][kk], acc[0][1][mi][ni]);
    __builtin_amdgcn_s_setprio(0);

    // ---- ph2: quadrant (1,1); needs A1; stage B1(T+1) ----
    if (st) VM4_BAR(); else VM0_BAR();
#pragma unroll
    for (int mi = 0; mi < 4; ++mi) {
      afr[mi][0] = *(const bf16x8*)(pa + 8192 + aRow + mi * 1024 + swz0);
      afr[mi][1] = *(const bf16x8*)(pa + 8192 + aRow + mi * 1024 + swz1);
    }
    if (st) STAGE_B(1, k64, d);
    LGK0_SB();
    __builtin_amdgcn_s_setprio(1);
#pragma unroll
    for (int mi = 0; mi < 4; ++mi)
#pragma unroll
      for (int ni = 0; ni < 2; ++ni)
#pragma unroll
        for (int kk = 0; kk < 2; ++kk)
          acc[1][1][mi][ni] = MF(afr[mi][kk], bfr[ni][kk], acc[1][1][mi][ni]);
    __builtin_amdgcn_s_setprio(0);

    // ---- ph3: quadrant (1,0); re-read B0 (still valid); stage A1(T+1) ----
    BAR_ONLY();
#pragma unroll
    for (int ni = 0; ni < 2; ++ni) {
      bfr[ni][0] = *(const bf16x8*)(pb + bRow + ni * 1024 + swz0);
      bfr[ni][1] = *(const bf16x8*)(pb + bRow + ni * 1024 + swz1);
    }
    if (st) STAGE_A(1, k64, d);
    LGK0_SB();
    __builtin_amdgcn_s_setprio(1);
#pragma unroll
    for (int mi = 0; mi < 4; ++mi)
#pragma unroll
      for (int ni = 0; ni < 2; ++ni)
#pragma unroll
        for (int kk = 0; kk < 2; ++kk)
          acc[1][0][mi][ni] = MF(afr[mi][kk], bfr[ni][kk], acc[1][0][mi][ni]);
    __builtin_amdgcn_s_setprio(0);
  }

  // epilogue
  bf16* Pb = (bf16*)((KSPLIT == 2 && ks) ? Cout2 : Cout);
#pragma unroll
  for (int qa = 0; qa < 2; ++qa)
#pragma unroll
    for (int mi = 0; mi < 4; ++mi) {
      int row = m0 + qa * 128 + wr + mi * 16 + lg * 4;
#pragma unroll
      for (int qb = 0; qb < 2; ++qb)
#pragma unroll
        for (int ni = 0; ni < 2; ++ni) {
          int col = n0 + qb * 128 + wc + ni * 16 + lr;
          float bv = (EPI == 3) ? 0.f : bias[col];
          f32x4 a = acc[qa][qb][mi][ni];
#pragma unroll
          for (int r = 0; r < 4; ++r) {
            float v = a[r] + bv;
            size_t idx = (size_t)(row + r) * N + col;
            if (EPI == 0)      Pb[idx] = (bf16)v;
            else if (EPI == 1) ((float*)Cout)[idx] = v + res[idx];
            else if (EPI == 2) Pb[idx] = (bf16)(0.5f * v * (1.f + erff(v * 0.70710678118654752f)));
            else               Pb[idx] = (bf16)v;
          }
        }
    }
#undef STAGE_A
#undef STAGE_B
}

// out = p0 + p1 + bias + res (f32), for split-K. 8 elems/thread, N=1024.
__global__ __launch_bounds__(256)
void combine2(const bf16* __restrict__ p0, const bf16* __restrict__ p1,
              const float* __restrict__ bias, const float* __restrict__ res,
              float* __restrict__ out)
{
  int i = (blockIdx.x * 256 + threadIdx.x) * 8;
  bf16x8 a = *(const bf16x8*)(p0 + i);
  bf16x8 b = *(const bf16x8*)(p1 + i);
  int c = i & 1023;
#pragma unroll
  for (int j = 0; j < 8; ++j)
    out[i + j] = (float)a[j] + (float)b[j] + bias[c + j] + res[i + j];
}

// LayerNorm over last dim (1024), fp32 in -> bf16 out. One block per row.
__global__ __launch_bounds__(256)
void ln_bf16(const float* __restrict__ x, const float* __restrict__ w,
             const float* __restrict__ b, bf16* __restrict__ out)
{
  int row = blockIdx.x;
  int t = threadIdx.x;
  float4 v = ((const float4*)(x + (size_t)row * 1024))[t];
  float s  = v.x + v.y + v.z + v.w;
  float sq = v.x * v.x + v.y * v.y + v.z * v.z + v.w * v.w;
#pragma unroll
  for (int off = 32; off >= 1; off >>= 1) {
    s  += __shfl_xor(s, off);
    sq += __shfl_xor(sq, off);
  }
  __shared__ float ps[4], pq[4];
  if ((t & 63) == 0) { ps[t >> 6] = s; pq[t >> 6] = sq; }
  __syncthreads();
  s  = ps[0] + ps[1] + ps[2] + ps[3];
  sq = pq[0] + pq[1] + pq[2] + pq[3];
  float mu  = s * (1.f / 1024.f);
  float var = sq * (1.f / 1024.f) - mu * mu;
  float rstd = rsqrtf(var + 1e-5f);
  float4 wv = ((const float4*)w)[t];
  float4 bv = ((const float4*)b)[t];
  size_t o0 = (size_t)row * 1024 + t * 4;
  out[o0 + 0] = (bf16)((v.x - mu) * rstd * wv.x + bv.x);
  out[o0 + 1] = (bf16)((v.y - mu) * rstd * wv.y + bv.y);
  out[o0 + 2] = (bf16)((v.z - mu) * rstd * wv.z + bv.z);
  out[o0 + 3] = (bf16)((v.w - mu) * rstd * wv.w + bv.w);
}

// WT[N,K] (bf16) = W[K,N] (f32) transposed+cast. grid=(K/32, N/32), 256 thr.
__global__ __launch_bounds__(256)
void transpose_cast(const float* __restrict__ W, bf16* __restrict__ WT, int K, int N)
{
  __shared__ float tile[32][33];
  int bk = blockIdx.x * 32, bn = blockIdx.y * 32;
  int tx = threadIdx.x & 31, ty = threadIdx.x >> 5;
#pragma unroll
  for (int i = ty; i < 32; i += 8)
    tile[i][tx] = W[(size_t)(bk + i) * N + bn + tx];
  __syncthreads();
#pragma unroll
  for (int i = ty; i < 32; i += 8)
    WT[(size_t)(bn + i) * K + bk + tx] = (bf16)tile[tx][i];
}

// V transpose: vt[(b*16+h)*64 + d][t] = qkv[(b*2048+t)*3072 + 2048 + h*64 + d]
__global__ __launch_bounds__(256)
void vtrans(const bf16* __restrict__ qkv, bf16* __restrict__ vt)
{
  __shared__ alignas(16) bf16 tile[64 * 64];
  int bh = blockIdx.x;
  int b = bh >> 4, h = bh & 15;
  int t0 = blockIdx.y * 64;
  int t = threadIdx.x;
#pragma unroll
  for (int i = 0; i < 2; ++i) {
    int c = i * 256 + t;
    int tt = c >> 3, d8 = c & 7;
    bf16x8 v = *(const bf16x8*)(qkv + (size_t)(b * 2048 + t0 + tt) * 3072 + 2048 + h * 64 + d8 * 8);
    *(bf16x8*)&tile[(tt * 8 + (d8 ^ (tt >> 3))) * 8] = v;
  }
  __syncthreads();
#pragma unroll
  for (int i = 0; i < 2; ++i) {
    int c = i * 256 + t;
    int d = c >> 3, tt8 = c & 7;
    bf16x8 o;
#pragma unroll
    for (int j = 0; j < 8; ++j) {
      int row = tt8 * 8 + j;
      o[j] = tile[(row * 8 + ((d >> 3) ^ (row >> 3))) * 8 + (d & 7)];
    }
    *(bf16x8*)(vt + (size_t)(bh * 64 + d) * 2048 + t0 + tt8 * 8) = o;
  }
}

// Flash causal attention, block-cooperative + fixed-cap softmax.
__global__ __launch_bounds__(256)
void attn_flash(const bf16* __restrict__ qkv, const bf16* __restrict__ vt,
                bf16* __restrict__ y)
{
  __shared__ alignas(16) bf16 lk[64 * 64];
  __shared__ alignas(16) bf16 lv[64 * 64];
  __shared__ alignas(16) bf16 lp[4][16 * 64];

  int bid = blockIdx.x;
  int bh = bid & 63;
  int qb = 31 - (bid >> 6);
  int b = bh >> 4, h = bh & 15;
  int t = threadIdx.x;
  int w = t >> 6, l = t & 63;
  int lr = l & 15, lg = l >> 4;
  int q0 = qb * 64;
  int qw = q0 + w * 16;
  const size_t RS = 3072;
  const float SCL = 0.18033688011112042f;   // 0.125 * log2(e)

  const bf16* qbase = qkv + (size_t)(b * 2048) * RS + h * 64;
  const bf16* kbase = qkv + (size_t)(b * 2048) * RS + 1024 + h * 64;
  const bf16* vtb   = vt + (size_t)(bh * 64) * 2048;

  bf16x8 qf[2];
#pragma unroll
  for (int kk = 0; kk < 2; ++kk)
    qf[kk] = *(const bf16x8*)(qbase + (size_t)(qw + lr) * RS + kk * 32 + lg * 8);

  f32x4 zero = {0.f, 0.f, 0.f, 0.f};
  f32x4 o[4];
#pragma unroll
  for (int ni = 0; ni < 4; ++ni) o[ni] = zero;
  float lo[4] = {0.f, 0.f, 0.f, 0.f};

  int nkb = qb + 1;
  for (int kb = 0; kb < nkb; ++kb) {
    int k0 = kb * 64;
#pragma unroll
    for (int i = 0; i < 2; ++i) {
      int c = i * 256 + t;
      int row = c >> 3, c8 = c & 7;
      int sc8 = c8 ^ (row & 7);
      gload_lds16(kbase + (size_t)(k0 + row) * RS + sc8 * 8, &lk[c * 8]);
      gload_lds16(vtb + (size_t)row * 2048 + k0 + sc8 * 8, &lv[c * 8]);
    }
    __syncthreads();

    f32x4 s[4];
#pragma unroll
    for (int j = 0; j < 4; ++j) s[j] = zero;
#pragma unroll
    for (int kk = 0; kk < 2; ++kk)
#pragma unroll
      for (int j = 0; j < 4; ++j) {
        int krow = j * 16 + lr;
        bf16x8 kf = *(const bf16x8*)&lk[krow * 64 + (((4 * kk + lg) ^ (krow & 7)) * 8)];
        s[j] = MF(qf[kk], kf, s[j]);
      }

    bool needmask = (kb == qb);
    float p[4][4];
#pragma unroll
    for (int r = 0; r < 4; ++r) {
      int tq = qw + lg * 4 + r;
#pragma unroll
      for (int j = 0; j < 4; ++j) {
        float v = s[j][r] * SCL;
        if (needmask && (k0 + j * 16 + lr > tq)) v = -1e30f;
        p[j][r] = exp2f(v);
      }
      lo[r] += (p[0][r] + p[1][r]) + (p[2][r] + p[3][r]);
    }

#pragma unroll
    for (int r = 0; r < 4; ++r) {
      int qr = lg * 4 + r;
#pragma unroll
      for (int j = 0; j < 4; ++j) {
        int ch = (2 * j + (lr >> 3)) ^ (qr & 7);
        lp[w][qr * 64 + ch * 8 + (lr & 7)] = (bf16)p[j][r];
      }
    }
    bf16x8 pa[2];
#pragma unroll
    for (int kf = 0; kf < 2; ++kf)
      pa[kf] = *(const bf16x8*)&lp[w][lr * 64 + (((4 * kf + lg) ^ (lr & 7)) * 8)];

#pragma unroll
    for (int ni = 0; ni < 4; ++ni)
#pragma unroll
      for (int kf = 0; kf < 2; ++kf) {
        int d = ni * 16 + lr;
        bf16x8 vf = *(const bf16x8*)&lv[d * 64 + (((4 * kf + lg) ^ (d & 7)) * 8)];
        o[ni] = MF(pa[kf], vf, o[ni]);
      }
    __syncthreads();
  }

#pragma unroll
  for (int r = 0; r < 4; ++r) {
#pragma unroll
    for (int off = 1; off < 16; off <<= 1) lo[r] += __shfl_xor(lo[r], off);
    lo[r] = 1.f / lo[r];
  }
#pragma unroll
  for (int ni = 0; ni < 4; ++ni)
#pragma unroll
    for (int r = 0; r < 4; ++r) {
      int tq = qw + lg * 4 + r;
      y[(size_t)(b * 2048 + tq) * 1024 + h * 64 + ni * 16 + lr] = (bf16)(o[ni][r] * lo[r]);
    }
}

extern "C" void kernel_launch(void* const* d_in, const int* in_sizes, int n_in,
                              void* d_out, int out_size, void* d_ws, size_t ws_size,
                              hipStream_t stream) {
  (void)in_sizes; (void)n_in; (void)out_size; (void)ws_size;
  const float* x      = (const float*)d_in[0];
  const float* ln1w   = (const float*)d_in[1];
  const float* ln1b   = (const float*)d_in[2];
  const float* ln2w   = (const float*)d_in[3];
  const float* ln2b   = (const float*)d_in[4];
  const float* w_attn = (const float*)d_in[5];
  const float* b_attn = (const float*)d_in[6];
  const float* w_proj = (const float*)d_in[7];
  const float* b_proj = (const float*)d_in[8];
  const float* w_fc   = (const float*)d_in[9];
  const float* b_fc   = (const float*)d_in[10];
  const float* w_fc2  = (const float*)d_in[11];
  const float* b_fc2  = (const float*)d_in[12];
  float* out = (float*)d_out;

  // workspace: h | [qkv | y] == m | x1 (vt overlays x1) | weightsT
  char* p = (char*)d_ws;
  bf16*  h     = (bf16*)p;  p += (size_t)8192 * 1024 * 2;
  bf16*  qkv   = (bf16*)p;
  bf16*  mbuf  = (bf16*)p;  p += (size_t)8192 * 3072 * 2;   // m overlays qkv+y
  bf16*  ybuf  = (bf16*)p;  p += (size_t)8192 * 1024 * 2;
  float* x1    = (float*)p; p += (size_t)8192 * 1024 * 4;
  bf16*  wqkvT = (bf16*)p;  p += (size_t)3072 * 1024 * 2;
  bf16*  wprojT= (bf16*)p;  p += (size_t)1024 * 1024 * 2;
  bf16*  wfcT  = (bf16*)p;  p += (size_t)4096 * 1024 * 2;
  bf16*  wfc2T = (bf16*)p;  p += (size_t)1024 * 4096 * 2;
  bf16*  vt    = (bf16*)x1;       // dead until proj writes x1 (after attn)
  // proj split-K partials: qkv region is dead after attn (16MB each)
  bf16*  pp0   = qkv;
  bf16*  pp1   = qkv + (size_t)8192 * 1024;
  // fc2 split-K partials: h dead after FC; wqkvT..wfcT contiguous 16MB dead
  bf16*  sp0   = h;
  bf16*  sp1   = wqkvT;

  transpose_cast<<<dim3(1024 / 32, 3072 / 32), 256, 0, stream>>>(w_attn, wqkvT, 1024, 3072);
  transpose_cast<<<dim3(1024 / 32, 1024 / 32), 256, 0, stream>>>(w_proj, wprojT, 1024, 1024);
  transpose_cast<<<dim3(1024 / 32, 4096 / 32), 256, 0, stream>>>(w_fc,   wfcT,  1024, 4096);
  transpose_cast<<<dim3(4096 / 32, 1024 / 32), 256, 0, stream>>>(w_fc2,  wfc2T, 4096, 1024);

  ln_bf16<<<8192, 256, 0, stream>>>(x, ln1w, ln1b, h);
  gemmq<0, 1><<<384, 512, 0, stream>>>(h, wqkvT, b_attn, nullptr, qkv, nullptr, 8192, 3072, 1024);
  vtrans<<<dim3(64, 32), 256, 0, stream>>>(qkv, vt);
  attn_flash<<<2048, 256, 0, stream>>>(qkv, vt, ybuf);
  gemmq<3, 2><<<256, 512, 0, stream>>>(ybuf, wprojT, nullptr, nullptr, pp0, pp1, 8192, 1024, 1024);
  combine2<<<4096, 256, 0, stream>>>(pp0, pp1, b_proj, x, x1);
  ln_bf16<<<8192, 256, 0, stream>>>(x1, ln2w, ln2b, h);
  gemmq<2, 1><<<512, 512, 0, stream>>>(h, wfcT, b_fc, nullptr, mbuf, nullptr, 8192, 4096, 1024);
  gemmq<3, 2><<<256, 512, 0, stream>>>(mbuf, wfc2T, nullptr, nullptr, sp0, sp1, 8192, 1024, 4096);
  combine2<<<4096, 256, 0, stream>>>(sp0, sp1, b_fc2, x1, out);
}

// Round 10
// 409.515 us; speedup vs baseline: 1.1447x; 1.0723x over previous
//
#include <hip/hip_runtime.h>
#include <hip/hip_bf16.h>
#include <math.h>

typedef __bf16 bf16;
typedef __bf16 bf16x4 __attribute__((ext_vector_type(4)));
typedef __bf16 bf16x8 __attribute__((ext_vector_type(8)));
typedef float f32x4 __attribute__((ext_vector_type(4)));

__device__ __forceinline__ void gload_lds16(const bf16* g, bf16* l) {
  __builtin_amdgcn_global_load_lds(
      (const __attribute__((address_space(1))) void*)g,
      (__attribute__((address_space(3))) void*)l, 16, 0, 0);
}

#define MF(a, b, c) __builtin_amdgcn_mfma_f32_16x16x32_bf16((a), (b), (c), 0, 0, 0)
// fused wait+barrier blocks (opaque: nothing can be scheduled across)
#define VM4_BAR()  asm volatile("s_waitcnt vmcnt(4)\ns_barrier" ::: "memory")
#define VM2_BAR()  asm volatile("s_waitcnt vmcnt(2)\ns_barrier" ::: "memory")
#define VM0_BAR()  asm volatile("s_waitcnt vmcnt(0)\ns_barrier" ::: "memory")
#define LGK0_SB()  do { asm volatile("s_waitcnt lgkmcnt(0)" ::: "memory"); \
                        __builtin_amdgcn_sched_barrier(0); } while (0)

// 256x256 8-wave GEMM, BK=64, [256][64] LDS tiles (128B rows, 0-conflict
// chunk-XOR swizzle), double-buffered, half-tile staging consumed by
// C-quadrant phases. B-halves held in regs across phases: ph3 is
// register-only (no barrier). Counted vmcnt(4), no mid-loop drain.
// C = A[M,K] @ BT[N,K]^T, bf16 in, fp32 accum.
// EPI 0: bf16 = acc+bias | 1: f32 = acc+bias+res | 2: bf16 = gelu(acc+bias)
// EPI 3: bf16 = acc (raw partial; KSPLIT=2: ks0->Cout, ks1->Cout2)
template <int EPI, int KSPLIT>
__global__ __launch_bounds__(512, 2)
void gemmq(const bf16* __restrict__ A, const bf16* __restrict__ BT,
           const float* __restrict__ bias, const float* __restrict__ res,
           void* __restrict__ Cout, void* __restrict__ Cout2,
           int M, int N, int K)
{
  __shared__ alignas(16) bf16 lsA[2][16384];   // [buf][256*64]  32KB each
  __shared__ alignas(16) bf16 lsB[2][16384];

  int nbn = N >> 8;
  int nwg = (M >> 8) * nbn;
  int bid = blockIdx.x;
  int ks = 0;
  if (KSPLIT == 2) { ks = (bid >= nwg) ? 1 : 0; bid -= ks * nwg; }
  int cpx = nwg >> 3;
  int wg  = (bid & 7) * cpx + (bid >> 3);      // XCD swizzle (bijective)
  int m0 = (wg / nbn) << 8;
  int n0 = (wg % nbn) << 8;

  int t = threadIdx.x;
  int l = t & 63, w = t >> 6;
  int wr = (w >> 2) << 6;        // 0 / 64   (M within half)
  int wc = (w & 3) << 5;         // 0/32/64/96 (N within half)
  int lr = l & 15, lg = l >> 4;

  int kb0 = (KSPLIT == 2) ? ks * (K >> 1) : 0;
  int nt = (K / KSPLIT) >> 6;

  const bf16* Ag = A  + (size_t)m0 * K + kb0;
  const bf16* Bg = BT + (size_t)n0 * K + kb0;

  // ds_read element offsets: chunk8 = (kk*4+lg) ^ (lr&7)  [0-conflict]
  int swz0 = (lg ^ (lr & 7)) << 3;     // kk=0 chunk, elements
  int swz1 = swz0 ^ 32;                // kk=1 (chunk^4)
  int aRow = (wr + lr) << 6;           // row*64 elements
  int bRow = (wc + lr) << 6;

  // staging: half = 128 rows = 2 x 1024B linear dest; inverse-swz source
  const bf16* srcA[2]; const bf16* srcB[2];
#pragma unroll
  for (int j = 0; j < 2; ++j) {
    int ci = j * 512 + t;
    int r = ci >> 3;
    int g = (ci & 7) ^ (r & 7);
    srcA[j] = Ag + (size_t)r * K + g * 8;
    srcB[j] = Bg + (size_t)r * K + g * 8;
  }
  size_t qA = (size_t)128 * K;         // half-1 source row offset

#define STAGE_A(q, kofs, db) do { \
  _Pragma("unroll") \
  for (int j = 0; j < 2; ++j) \
    gload_lds16(srcA[j] + (q) * qA + (kofs), &lsA[db][(q) * 8192 + (j * 512 + t) * 8]); \
} while (0)
#define STAGE_B(q, kofs, db) do { \
  _Pragma("unroll") \
  for (int j = 0; j < 2; ++j) \
    gload_lds16(srcB[j] + (q) * qA + (kofs), &lsB[db][(q) * 8192 + (j * 512 + t) * 8]); \
} while (0)

  f32x4 acc[2][2][4][2];
  f32x4 zero = {0.f, 0.f, 0.f, 0.f};
#pragma unroll
  for (int qa = 0; qa < 2; ++qa)
#pragma unroll
    for (int qb = 0; qb < 2; ++qb)
#pragma unroll
      for (int mi = 0; mi < 4; ++mi)
#pragma unroll
        for (int ni = 0; ni < 2; ++ni) acc[qa][qb][mi][ni] = zero;

  // prologue: tile 0 halves in steady-state order A0,B0,B1,A1
  STAGE_A(0, 0, 0);
  STAGE_B(0, 0, 0);
  STAGE_B(1, 0, 0);
  STAGE_A(1, 0, 0);

  bf16x8 afr[4][2], bfr0[2][2], bfr1[2][2];

  for (int T = 0; T < nt; ++T) {
    int c = T & 1, d = c ^ 1;
    bool st = (T + 1 < nt);
    int k64 = (T + 1) << 6;
    const bf16* pa = &lsA[c][0];
    const bf16* pb = &lsB[c][0];

    // ---- ph0: Q(0,0); A0,B0 resident; stage A0(T+1) ----
    VM4_BAR();
#pragma unroll
    for (int mi = 0; mi < 4; ++mi) {
      afr[mi][0] = *(const bf16x8*)(pa + aRow + mi * 1024 + swz0);
      afr[mi][1] = *(const bf16x8*)(pa + aRow + mi * 1024 + swz1);
    }
#pragma unroll
    for (int ni = 0; ni < 2; ++ni) {
      bfr0[ni][0] = *(const bf16x8*)(pb + bRow + ni * 1024 + swz0);
      bfr0[ni][1] = *(const bf16x8*)(pb + bRow + ni * 1024 + swz1);
    }
    if (st) STAGE_A(0, k64, d);
    LGK0_SB();
    __builtin_amdgcn_s_setprio(1);
#pragma unroll
    for (int mi = 0; mi < 4; ++mi)
#pragma unroll
      for (int ni = 0; ni < 2; ++ni)
#pragma unroll
        for (int kk = 0; kk < 2; ++kk)
          acc[0][0][mi][ni] = MF(afr[mi][kk], bfr0[ni][kk], acc[0][0][mi][ni]);
    __builtin_amdgcn_s_setprio(0);

    // ---- ph1: Q(0,1); B1 resident; stage B0(T+1) ----
    if (st) VM4_BAR(); else VM2_BAR();
#pragma unroll
    for (int ni = 0; ni < 2; ++ni) {
      bfr1[ni][0] = *(const bf16x8*)(pb + 8192 + bRow + ni * 1024 + swz0);
      bfr1[ni][1] = *(const bf16x8*)(pb + 8192 + bRow + ni * 1024 + swz1);
    }
    if (st) STAGE_B(0, k64, d);
    LGK0_SB();
    __builtin_amdgcn_s_setprio(1);
#pragma unroll
    for (int mi = 0; mi < 4; ++mi)
#pragma unroll
      for (int ni = 0; ni < 2; ++ni)
#pragma unroll
        for (int kk = 0; kk < 2; ++kk)
          acc[0][1][mi][ni] = MF(afr[mi][kk], bfr1[ni][kk], acc[0][1][mi][ni]);
    __builtin_amdgcn_s_setprio(0);

    // ---- ph2: Q(1,1); A1 resident; stage B1(T+1) ----
    if (st) VM4_BAR(); else VM0_BAR();
#pragma unroll
    for (int mi = 0; mi < 4; ++mi) {
      afr[mi][0] = *(const bf16x8*)(pa + 8192 + aRow + mi * 1024 + swz0);
      afr[mi][1] = *(const bf16x8*)(pa + 8192 + aRow + mi * 1024 + swz1);
    }
    if (st) STAGE_B(1, k64, d);
    LGK0_SB();
    __builtin_amdgcn_s_setprio(1);
#pragma unroll
    for (int mi = 0; mi < 4; ++mi)
#pragma unroll
      for (int ni = 0; ni < 2; ++ni)
#pragma unroll
        for (int kk = 0; kk < 2; ++kk)
          acc[1][1][mi][ni] = MF(afr[mi][kk], bfr1[ni][kk], acc[1][1][mi][ni]);
    __builtin_amdgcn_s_setprio(0);

    // ---- ph3: Q(1,0); register-only (afr=A1, bfr0=B0); no barrier ----
    if (st) STAGE_A(1, k64, d);
    __builtin_amdgcn_s_setprio(1);
#pragma unroll
    for (int mi = 0; mi < 4; ++mi)
#pragma unroll
      for (int ni = 0; ni < 2; ++ni)
#pragma unroll
        for (int kk = 0; kk < 2; ++kk)
          acc[1][0][mi][ni] = MF(afr[mi][kk], bfr0[ni][kk], acc[1][0][mi][ni]);
    __builtin_amdgcn_s_setprio(0);
  }

  // epilogue
  bf16* Pb = (bf16*)((KSPLIT == 2 && ks) ? Cout2 : Cout);
#pragma unroll
  for (int qa = 0; qa < 2; ++qa)
#pragma unroll
    for (int mi = 0; mi < 4; ++mi) {
      int row = m0 + qa * 128 + wr + mi * 16 + lg * 4;
#pragma unroll
      for (int qb = 0; qb < 2; ++qb)
#pragma unroll
        for (int ni = 0; ni < 2; ++ni) {
          int col = n0 + qb * 128 + wc + ni * 16 + lr;
          float bv = (EPI == 3) ? 0.f : bias[col];
          f32x4 a = acc[qa][qb][mi][ni];
#pragma unroll
          for (int r = 0; r < 4; ++r) {
            float v = a[r] + bv;
            size_t idx = (size_t)(row + r) * N + col;
            if (EPI == 0)      Pb[idx] = (bf16)v;
            else if (EPI == 1) ((float*)Cout)[idx] = v + res[idx];
            else if (EPI == 2) Pb[idx] = (bf16)(0.5f * v * (1.f + erff(v * 0.70710678118654752f)));
            else               Pb[idx] = (bf16)v;
          }
        }
    }
#undef STAGE_A
#undef STAGE_B
}

// out = p0 + p1 + bias + res (f32), for split-K. 8 elems/thread, N=1024.
__global__ __launch_bounds__(256)
void combine2(const bf16* __restrict__ p0, const bf16* __restrict__ p1,
              const float* __restrict__ bias, const float* __restrict__ res,
              float* __restrict__ out)
{
  int i = (blockIdx.x * 256 + threadIdx.x) * 8;
  bf16x8 a = *(const bf16x8*)(p0 + i);
  bf16x8 b = *(const bf16x8*)(p1 + i);
  int c = i & 1023;
#pragma unroll
  for (int j = 0; j < 8; ++j)
    out[i + j] = (float)a[j] + (float)b[j] + bias[c + j] + res[i + j];
}

// Fused: x1 = p0+p1+bias+res (f32 out), h = LN(x1)*w+b (bf16 out).
// One block per row (1024), 256 thr x 4 elems. Saves a full x1 re-read.
__global__ __launch_bounds__(256)
void combine_ln(const bf16* __restrict__ p0, const bf16* __restrict__ p1,
                const float* __restrict__ bias, const float* __restrict__ res,
                const float* __restrict__ lnw, const float* __restrict__ lnb,
                float* __restrict__ x1, bf16* __restrict__ hout)
{
  int row = blockIdx.x;
  int t = threadIdx.x;
  size_t i0 = (size_t)row * 1024 + t * 4;
  bf16x4 a = *(const bf16x4*)(p0 + i0);
  bf16x4 b = *(const bf16x4*)(p1 + i0);
  float4 r = *(const float4*)(res + i0);
  float4 bi = ((const float4*)bias)[t];
  float v0 = (float)a[0] + (float)b[0] + bi.x + r.x;
  float v1 = (float)a[1] + (float)b[1] + bi.y + r.y;
  float v2 = (float)a[2] + (float)b[2] + bi.z + r.z;
  float v3 = (float)a[3] + (float)b[3] + bi.w + r.w;
  float4 vv = {v0, v1, v2, v3};
  *(float4*)(x1 + i0) = vv;
  float s  = v0 + v1 + v2 + v3;
  float sq = v0 * v0 + v1 * v1 + v2 * v2 + v3 * v3;
#pragma unroll
  for (int off = 32; off >= 1; off >>= 1) {
    s  += __shfl_xor(s, off);
    sq += __shfl_xor(sq, off);
  }
  __shared__ float ps[4], pq[4];
  if ((t & 63) == 0) { ps[t >> 6] = s; pq[t >> 6] = sq; }
  __syncthreads();
  s  = ps[0] + ps[1] + ps[2] + ps[3];
  sq = pq[0] + pq[1] + pq[2] + pq[3];
  float mu  = s * (1.f / 1024.f);
  float var = sq * (1.f / 1024.f) - mu * mu;
  float rstd = rsqrtf(var + 1e-5f);
  float4 wv = ((const float4*)lnw)[t];
  float4 bv = ((const float4*)lnb)[t];
  hout[i0 + 0] = (bf16)((v0 - mu) * rstd * wv.x + bv.x);
  hout[i0 + 1] = (bf16)((v1 - mu) * rstd * wv.y + bv.y);
  hout[i0 + 2] = (bf16)((v2 - mu) * rstd * wv.z + bv.z);
  hout[i0 + 3] = (bf16)((v3 - mu) * rstd * wv.w + bv.w);
}

// LayerNorm over last dim (1024), fp32 in -> bf16 out. One block per row.
__global__ __launch_bounds__(256)
void ln_bf16(const float* __restrict__ x, const float* __restrict__ w,
             const float* __restrict__ b, bf16* __restrict__ out)
{
  int row = blockIdx.x;
  int t = threadIdx.x;
  float4 v = ((const float4*)(x + (size_t)row * 1024))[t];
  float s  = v.x + v.y + v.z + v.w;
  float sq = v.x * v.x + v.y * v.y + v.z * v.z + v.w * v.w;
#pragma unroll
  for (int off = 32; off >= 1; off >>= 1) {
    s  += __shfl_xor(s, off);
    sq += __shfl_xor(sq, off);
  }
  __shared__ float ps[4], pq[4];
  if ((t & 63) == 0) { ps[t >> 6] = s; pq[t >> 6] = sq; }
  __syncthreads();
  s  = ps[0] + ps[1] + ps[2] + ps[3];
  sq = pq[0] + pq[1] + pq[2] + pq[3];
  float mu  = s * (1.f / 1024.f);
  float var = sq * (1.f / 1024.f) - mu * mu;
  float rstd = rsqrtf(var + 1e-5f);
  float4 wv = ((const float4*)w)[t];
  float4 bv = ((const float4*)b)[t];
  size_t o0 = (size_t)row * 1024 + t * 4;
  out[o0 + 0] = (bf16)((v.x - mu) * rstd * wv.x + bv.x);
  out[o0 + 1] = (bf16)((v.y - mu) * rstd * wv.y + bv.y);
  out[o0 + 2] = (bf16)((v.z - mu) * rstd * wv.z + bv.z);
  out[o0 + 3] = (bf16)((v.w - mu) * rstd * wv.w + bv.w);
}

// WT[N,K] (bf16) = W[K,N] (f32) transposed+cast. grid=(K/32, N/32), 256 thr.
__global__ __launch_bounds__(256)
void transpose_cast(const float* __restrict__ W, bf16* __restrict__ WT, int K, int N)
{
  __shared__ float tile[32][33];
  int bk = blockIdx.x * 32, bn = blockIdx.y * 32;
  int tx = threadIdx.x & 31, ty = threadIdx.x >> 5;
#pragma unroll
  for (int i = ty; i < 32; i += 8)
    tile[i][tx] = W[(size_t)(bk + i) * N + bn + tx];
  __syncthreads();
#pragma unroll
  for (int i = ty; i < 32; i += 8)
    WT[(size_t)(bn + i) * K + bk + tx] = (bf16)tile[tx][i];
}

// V transpose: vt[(b*16+h)*64 + d][t] = qkv[(b*2048+t)*3072 + 2048 + h*64 + d]
__global__ __launch_bounds__(256)
void vtrans(const bf16* __restrict__ qkv, bf16* __restrict__ vt)
{
  __shared__ alignas(16) bf16 tile[64 * 64];
  int bh = blockIdx.x;
  int b = bh >> 4, h = bh & 15;
  int t0 = blockIdx.y * 64;
  int t = threadIdx.x;
#pragma unroll
  for (int i = 0; i < 2; ++i) {
    int c = i * 256 + t;
    int tt = c >> 3, d8 = c & 7;
    bf16x8 v = *(const bf16x8*)(qkv + (size_t)(b * 2048 + t0 + tt) * 3072 + 2048 + h * 64 + d8 * 8);
    *(bf16x8*)&tile[(tt * 8 + (d8 ^ (tt >> 3))) * 8] = v;
  }
  __syncthreads();
#pragma unroll
  for (int i = 0; i < 2; ++i) {
    int c = i * 256 + t;
    int d = c >> 3, tt8 = c & 7;
    bf16x8 o;
#pragma unroll
    for (int j = 0; j < 8; ++j) {
      int row = tt8 * 8 + j;
      o[j] = tile[(row * 8 + ((d >> 3) ^ (row >> 3))) * 8 + (d & 7)];
    }
    *(bf16x8*)(vt + (size_t)(bh * 64 + d) * 2048 + t0 + tt8 * 8) = o;
  }
}

// Flash causal attention, block-cooperative + fixed-cap softmax.
// NEW: double-buffered K/V staging — single fused vmcnt(0)+barrier per tile
// (wait lands after a full tile of compute; stage next tile right after).
__global__ __launch_bounds__(256)
void attn_flash(const bf16* __restrict__ qkv, const bf16* __restrict__ vt,
                bf16* __restrict__ y)
{
  __shared__ alignas(16) bf16 lk[2][4096];
  __shared__ alignas(16) bf16 lv[2][4096];
  __shared__ alignas(16) bf16 lp[4][16 * 64];

  int bid = blockIdx.x;
  int bh = bid & 63;
  int qb = 31 - (bid >> 6);
  int b = bh >> 4, h = bh & 15;
  int t = threadIdx.x;
  int w = t >> 6, l = t & 63;
  int lr = l & 15, lg = l >> 4;
  int q0 = qb * 64;
  int qw = q0 + w * 16;
  const size_t RS = 3072;
  const float SCL = 0.18033688011112042f;   // 0.125 * log2(e)

  const bf16* qbase = qkv + (size_t)(b * 2048) * RS + h * 64;
  const bf16* kbase = qkv + (size_t)(b * 2048) * RS + 1024 + h * 64;
  const bf16* vtb   = vt + (size_t)(bh * 64) * 2048;

  bf16x8 qf[2];
#pragma unroll
  for (int kk = 0; kk < 2; ++kk)
    qf[kk] = *(const bf16x8*)(qbase + (size_t)(qw + lr) * RS + kk * 32 + lg * 8);

  // per-thread staging pointers (2 chunks each of K-tile and V^T-tile)
  const bf16* pK[2]; const bf16* pV[2]; int dst[2];
#pragma unroll
  for (int i = 0; i < 2; ++i) {
    int c = i * 256 + t;
    int row = c >> 3, c8 = c & 7;
    int sc8 = c8 ^ (row & 7);
    pK[i] = kbase + (size_t)row * RS + sc8 * 8;
    pV[i] = vtb + (size_t)row * 2048 + sc8 * 8;
    dst[i] = c * 8;
  }

  f32x4 zero = {0.f, 0.f, 0.f, 0.f};
  f32x4 o[4];
#pragma unroll
  for (int ni = 0; ni < 4; ++ni) o[ni] = zero;
  float lo[4] = {0.f, 0.f, 0.f, 0.f};

  int nkb = qb + 1;
  // prologue: stage tile 0 into buf 0
#pragma unroll
  for (int i = 0; i < 2; ++i) {
    gload_lds16(pK[i], &lk[0][dst[i]]);
    gload_lds16(pV[i], &lv[0][dst[i]]);
  }

  for (int kb = 0; kb < nkb; ++kb) {
    int cur = kb & 1;
    int k0 = kb * 64;
    VM0_BAR();                       // tile kb resident; all waves synced
    if (kb + 1 < nkb) {
#pragma unroll
      for (int i = 0; i < 2; ++i) {
        pK[i] += 64 * RS;
        pV[i] += 64;
        gload_lds16(pK[i], &lk[cur ^ 1][dst[i]]);
        gload_lds16(pV[i], &lv[cur ^ 1][dst[i]]);
      }
    }

    f32x4 s[4];
#pragma unroll
    for (int j = 0; j < 4; ++j) s[j] = zero;
#pragma unroll
    for (int kk = 0; kk < 2; ++kk)
#pragma unroll
      for (int j = 0; j < 4; ++j) {
        int krow = j * 16 + lr;
        bf16x8 kf = *(const bf16x8*)&lk[cur][krow * 64 + (((4 * kk + lg) ^ (krow & 7)) * 8)];
        s[j] = MF(qf[kk], kf, s[j]);
      }

    bool needmask = (kb == qb);
    float p[4][4];
#pragma unroll
    for (int r = 0; r < 4; ++r) {
      int tq = qw + lg * 4 + r;
#pragma unroll
      for (int j = 0; j < 4; ++j) {
        float v = s[j][r] * SCL;
        if (needmask && (k0 + j * 16 + lr > tq)) v = -1e30f;
        p[j][r] = exp2f(v);
      }
      lo[r] += (p[0][r] + p[1][r]) + (p[2][r] + p[3][r]);
    }

#pragma unroll
    for (int r = 0; r < 4; ++r) {
      int qr = lg * 4 + r;
#pragma unroll
      for (int j = 0; j < 4; ++j) {
        int ch = (2 * j + (lr >> 3)) ^ (qr & 7);
        lp[w][qr * 64 + ch * 8 + (lr & 7)] = (bf16)p[j][r];
      }
    }
    bf16x8 pa[2];
#pragma unroll
    for (int kf = 0; kf < 2; ++kf)
      pa[kf] = *(const bf16x8*)&lp[w][lr * 64 + (((4 * kf + lg) ^ (lr & 7)) * 8)];

#pragma unroll
    for (int ni = 0; ni < 4; ++ni)
#pragma unroll
      for (int kf = 0; kf < 2; ++kf) {
        int d = ni * 16 + lr;
        bf16x8 vf = *(const bf16x8*)&lv[cur][d * 64 + (((4 * kf + lg) ^ (d & 7)) * 8)];
        o[ni] = MF(pa[kf], vf, o[ni]);
      }
  }

#pragma unroll
  for (int r = 0; r < 4; ++r) {
#pragma unroll
    for (int off = 1; off < 16; off <<= 1) lo[r] += __shfl_xor(lo[r], off);
    lo[r] = 1.f / lo[r];
  }
#pragma unroll
  for (int ni = 0; ni < 4; ++ni)
#pragma unroll
    for (int r = 0; r < 4; ++r) {
      int tq = qw + lg * 4 + r;
      y[(size_t)(b * 2048 + tq) * 1024 + h * 64 + ni * 16 + lr] = (bf16)(o[ni][r] * lo[r]);
    }
}

extern "C" void kernel_launch(void* const* d_in, const int* in_sizes, int n_in,
                              void* d_out, int out_size, void* d_ws, size_t ws_size,
                              hipStream_t stream) {
  (void)in_sizes; (void)n_in; (void)out_size; (void)ws_size;
  const float* x      = (const float*)d_in[0];
  const float* ln1w   = (const float*)d_in[1];
  const float* ln1b   = (const float*)d_in[2];
  const float* ln2w   = (const float*)d_in[3];
  const float* ln2b   = (const float*)d_in[4];
  const float* w_attn = (const float*)d_in[5];
  const float* b_attn = (const float*)d_in[6];
  const float* w_proj = (const float*)d_in[7];
  const float* b_proj = (const float*)d_in[8];
  const float* w_fc   = (const float*)d_in[9];
  const float* b_fc   = (const float*)d_in[10];
  const float* w_fc2  = (const float*)d_in[11];
  const float* b_fc2  = (const float*)d_in[12];
  float* out = (float*)d_out;

  // workspace: h | [qkv | y] == m | x1 (vt overlays x1) | weightsT
  char* p = (char*)d_ws;
  bf16*  h     = (bf16*)p;  p += (size_t)8192 * 1024 * 2;
  bf16*  qkv   = (bf16*)p;
  bf16*  mbuf  = (bf16*)p;  p += (size_t)8192 * 3072 * 2;   // m overlays qkv+y
  bf16*  ybuf  = (bf16*)p;  p += (size_t)8192 * 1024 * 2;
  float* x1    = (float*)p; p += (size_t)8192 * 1024 * 4;
  bf16*  wqkvT = (bf16*)p;  p += (size_t)3072 * 1024 * 2;
  bf16*  wprojT= (bf16*)p;  p += (size_t)1024 * 1024 * 2;
  bf16*  wfcT  = (bf16*)p;  p += (size_t)4096 * 1024 * 2;
  bf16*  wfc2T = (bf16*)p;  p += (size_t)1024 * 4096 * 2;
  bf16*  vt    = (bf16*)x1;       // dead until combine_ln writes x1
  // proj split-K partials: qkv region dead after attn (16MB each)
  bf16*  pp0   = qkv;
  bf16*  pp1   = qkv + (size_t)8192 * 1024;
  // fc2 split-K partials: h dead after FC; wqkvT.. 16MB dead
  bf16*  sp0   = h;
  bf16*  sp1   = wqkvT;

  transpose_cast<<<dim3(1024 / 32, 3072 / 32), 256, 0, stream>>>(w_attn, wqkvT, 1024, 3072);
  transpose_cast<<<dim3(1024 / 32, 1024 / 32), 256, 0, stream>>>(w_proj, wprojT, 1024, 1024);
  transpose_cast<<<dim3(1024 / 32, 4096 / 32), 256, 0, stream>>>(w_fc,   wfcT,  1024, 4096);
  transpose_cast<<<dim3(4096 / 32, 1024 / 32), 256, 0, stream>>>(w_fc2,  wfc2T, 4096, 1024);

  ln_bf16<<<8192, 256, 0, stream>>>(x, ln1w, ln1b, h);
  gemmq<0, 1><<<384, 512, 0, stream>>>(h, wqkvT, b_attn, nullptr, qkv, nullptr, 8192, 3072, 1024);
  vtrans<<<dim3(64, 32), 256, 0, stream>>>(qkv, vt);
  attn_flash<<<2048, 256, 0, stream>>>(qkv, vt, ybuf);
  gemmq<3, 2><<<256, 512, 0, stream>>>(ybuf, wprojT, nullptr, nullptr, pp0, pp1, 8192, 1024, 1024);
  combine_ln<<<8192, 256, 0, stream>>>(pp0, pp1, b_proj, x, ln2w, ln2b, x1, h);
  gemmq<2, 1><<<512, 512, 0, stream>>>(h, wfcT, b_fc, nullptr, mbuf, nullptr, 8192, 4096, 1024);
  gemmq<3, 2><<<256, 512, 0, stream>>>(mbuf, wfc2T, nullptr, nullptr, sp0, sp1, 8192, 1024, 4096);
  combine2<<<4096, 256, 0, stream>>>(sp0, sp1, b_fc2, x1, out);
}